// Round 1
// baseline (547.302 us; speedup 1.0000x reference)
//
#include <hip/hip_runtime.h>

// Weighted segment-sum (graph attention aggregate), sorted segment_ids.
// out[n,f] = sum_{e in [offs[n], offs[n+1])} att[e] * neigh[e,f] + bias[f]
//
// R2: offsets precompute (kernel 1) + one-wave-per-node gather (kernel 2).
// R3: manual depth-1 software pipeline in the main loop. The compiler's
// natural emission for the R2 loop was [issue loads; waitcnt; FMA; branch]
// -- one 2KB stage in flight per wave, full loaded-HBM-latency per
// iteration, and with only ~4 iterations/wave (avg 32 edges) the loop
// never hides latency. Now stage i+1's loads (explicit registers) are
// issued BEFORE stage i's FMAs, so the waitcnt for stage i+1 lands one
// iteration later: 2 stages (4KB/wave incl. att) outstanding, and the
// per-iteration stall shrinks from ~full latency to latency minus one
// stage of issue+FMA work.

#define FEAT 64

// ---- kernel 1: segment boundaries -----------------------------------------
__global__ __launch_bounds__(256) void boundaries_kernel(
    const int* __restrict__ seg,   // [E], sorted
    int* __restrict__ offs,        // [N+1]
    int n_edges, int n_nodes)
{
    const int e = blockIdx.x * blockDim.x + threadIdx.x;
    if (e >= n_edges) return;
    const int s = seg[e];
    if (e == 0) {
        for (int n = 0; n <= s; ++n) offs[n] = 0;
    } else {
        const int sp = seg[e - 1];
        if (sp != s)
            for (int n = sp + 1; n <= s; ++n) offs[n] = e;
    }
    if (e == n_edges - 1) {
        for (int n = s + 1; n <= n_nodes; ++n) offs[n] = n_edges;
    }
}

// ---- kernel 2: one wave per node, gather + weighted sum -------------------
__global__ __launch_bounds__(256) void segsum_kernel(
    const float* __restrict__ neigh,   // [E, 64]
    const float* __restrict__ att,     // [E]
    const float* __restrict__ bias,    // [64]
    const int*   __restrict__ offs,    // [N+1]
    float* __restrict__ out,           // [N, 64]
    int n_nodes)
{
    const int wave_id = (blockIdx.x * blockDim.x + threadIdx.x) >> 6;
    const int lane    = threadIdx.x & 63;
    if (wave_id >= n_nodes) return;
    const int node = wave_id;

    const int start = offs[node];
    const int end   = offs[node + 1];

    const int rowgrp = lane >> 4;        // 0..3: which row of the 4-row group
    const int colgrp = lane & 15;        // columns 4*colgrp .. +3
    const size_t coloff = (size_t)colgrp * 4;

    float4 acc0 = make_float4(0.f, 0.f, 0.f, 0.f);
    float4 acc1 = make_float4(0.f, 0.f, 0.f, 0.f);

    int e = start;
    // Main loop: 8 rows (2048 B) per stage, depth-1 pipelined.
    if (e + 8 <= end) {
        // prologue: issue stage 0
        int r0 = e + rowgrp;
        int r1 = e + 4 + rowgrp;
        float  a0 = att[r0];
        float4 v0 = *(const float4*)(neigh + (size_t)r0 * FEAT + coloff);
        float  a1 = att[r1];
        float4 v1 = *(const float4*)(neigh + (size_t)r1 * FEAT + coloff);

        for (; e + 16 <= end; e += 8) {
            // issue stage i+1 BEFORE consuming stage i
            const int q0 = e + 8 + rowgrp;
            const int q1 = e + 12 + rowgrp;
            const float  na0 = att[q0];
            const float4 nv0 = *(const float4*)(neigh + (size_t)q0 * FEAT + coloff);
            const float  na1 = att[q1];
            const float4 nv1 = *(const float4*)(neigh + (size_t)q1 * FEAT + coloff);

            // consume stage i
            acc0.x = fmaf(a0, v0.x, acc0.x);
            acc0.y = fmaf(a0, v0.y, acc0.y);
            acc0.z = fmaf(a0, v0.z, acc0.z);
            acc0.w = fmaf(a0, v0.w, acc0.w);
            acc1.x = fmaf(a1, v1.x, acc1.x);
            acc1.y = fmaf(a1, v1.y, acc1.y);
            acc1.z = fmaf(a1, v1.z, acc1.z);
            acc1.w = fmaf(a1, v1.w, acc1.w);

            a0 = na0; v0 = nv0;
            a1 = na1; v1 = nv1;
        }

        // drain last stage
        acc0.x = fmaf(a0, v0.x, acc0.x);
        acc0.y = fmaf(a0, v0.y, acc0.y);
        acc0.z = fmaf(a0, v0.z, acc0.z);
        acc0.w = fmaf(a0, v0.w, acc0.w);
        acc1.x = fmaf(a1, v1.x, acc1.x);
        acc1.y = fmaf(a1, v1.y, acc1.y);
        acc1.z = fmaf(a1, v1.z, acc1.z);
        acc1.w = fmaf(a1, v1.w, acc1.w);
        e += 8;
    }

    // 4-row step.
    if (e + 4 <= end) {
        const int r = e + rowgrp;
        const float  a = att[r];
        const float4 v = *(const float4*)(neigh + (size_t)r * FEAT + coloff);
        acc0.x = fmaf(a, v.x, acc0.x);
        acc0.y = fmaf(a, v.y, acc0.y);
        acc0.z = fmaf(a, v.z, acc0.z);
        acc0.w = fmaf(a, v.w, acc0.w);
        e += 4;
    }
    // Tail: up to 3 rows, predicated per row-group.
    if (e + rowgrp < end) {
        const int r = e + rowgrp;
        const float  a = att[r];
        const float4 v = *(const float4*)(neigh + (size_t)r * FEAT + coloff);
        acc1.x = fmaf(a, v.x, acc1.x);
        acc1.y = fmaf(a, v.y, acc1.y);
        acc1.z = fmaf(a, v.z, acc1.z);
        acc1.w = fmaf(a, v.w, acc1.w);
    }

    float4 acc;
    acc.x = acc0.x + acc1.x;
    acc.y = acc0.y + acc1.y;
    acc.z = acc0.z + acc1.z;
    acc.w = acc0.w + acc1.w;

    // Fold the 4 row-groups (lanes l, l+16, l+32, l+48) into lanes 0..15.
    #pragma unroll
    for (int off = 32; off >= 16; off >>= 1) {
        acc.x += __shfl_down(acc.x, off);
        acc.y += __shfl_down(acc.y, off);
        acc.z += __shfl_down(acc.z, off);
        acc.w += __shfl_down(acc.w, off);
    }

    if (rowgrp == 0) {
        const float4 b = *(const float4*)(bias + colgrp * 4);
        float4 o;
        o.x = acc.x + b.x;
        o.y = acc.y + b.y;
        o.z = acc.z + b.z;
        o.w = acc.w + b.w;
        *(float4*)(out + (size_t)node * FEAT + colgrp * 4) = o;
    }
}

extern "C" void kernel_launch(void* const* d_in, const int* in_sizes, int n_in,
                              void* d_out, int out_size, void* d_ws, size_t ws_size,
                              hipStream_t stream) {
    // Inputs (setup_inputs order): nodes [N,64] (UNUSED by reference),
    // neighbor_feats [E,64], attention [E], bias [64], segment_ids [E].
    const float* neigh = (const float*)d_in[1];
    const float* att   = (const float*)d_in[2];
    const float* bias  = (const float*)d_in[3];
    const int*   seg   = (const int*)d_in[4];
    float* out = (float*)d_out;

    const int n_edges = in_sizes[2];           // attention is [E]
    const int n_nodes = out_size / FEAT;       // 50000

    int* offs = (int*)d_ws;                    // (N+1) ints, d_ws is plenty

    boundaries_kernel<<<(n_edges + 255) / 256, 256, 0, stream>>>(
        seg, offs, n_edges, n_nodes);

    const int waves_per_block = 256 / 64;      // 4 nodes per block
    const int blocks = (n_nodes + waves_per_block - 1) / waves_per_block;
    segsum_kernel<<<blocks, 256, 0, stream>>>(neigh, att, bias, offs, out,
                                              n_nodes);
}